// Round 2
// baseline (38260.779 us; speedup 1.0000x reference)
//
#include <hip/hip_runtime.h>
#include <hip/hip_bf16.h>

// ACOPF Gauss-Newton, matrix-free CGLS, single-workgroup LDS-resident solver.
// R2: exact diag(J^T J) Jacobi preconditioner, tolerance-based CG (rel 1e-6)
// with double-precision reductions and residual replacement every 64 iters.

#define NBUS 1000
#define NLINE 2000
#define NGEN 100
#define NLOAD 500
#define NNG 900    // n_nongen  (Vm unknowns; also count of Q rows)
#define NNR 999    // n_nonref  (Va unknowns; also count of P rows)
#define NX 1899
#define NTH 1024
#define NWAVE (NTH / 64)
#define MAXSTEPS 10
#define KCG_MAX 600
#define RIDGE_F 1e-6f

struct Ws {
  int   vm_pos[NBUS];   // rank in nongen list, or -1 if gen bus
  int   va_pos[NBUS];   // rank in nonref list, or -1 if ref bus
  float Pspec[NBUS];
  float Qspec[NBUS];
  float Vgb[NBUS];
};

// ---- dtype-robust load/store (auto-detected bf16 vs f32) -------------------
__device__ __forceinline__ float rdf(const void* p, int i, int bf) {
  if (bf) {
    unsigned int u = ((unsigned int)(((const unsigned short*)p)[i])) << 16;
    return __uint_as_float(u);
  }
  return ((const float*)p)[i];
}
__device__ __forceinline__ void wrf(void* p, int i, float v, int bf) {
  if (bf) {
    unsigned int u = __float_as_uint(v);
    unsigned int r = (u + 0x7fffu + ((u >> 16) & 1u)) >> 16;  // RNE
    ((unsigned short*)p)[i] = (unsigned short)r;
  } else {
    ((float*)p)[i] = v;
  }
}
__device__ __forceinline__ int detect_bf(const void* p) {
  const unsigned short* h = (const unsigned short*)p;
  int ok = 1;
#pragma unroll
  for (int i = 0; i < 8; ++i) {
    float v = __uint_as_float(((unsigned int)h[i]) << 16);
    ok &= (v > 0.25f && v < 8.0f) ? 1 : 0;
  }
  return ok;
}

__device__ __forceinline__ int lbound(const int* a, int n, int v) {
  int lo = 0, hi = n;
  while (lo < hi) { int m = (lo + hi) >> 1; if (a[m] < v) lo = m + 1; else hi = m; }
  return lo;
}

// ---- line admittance, recomputed per pass ----------------------------------
struct In {
  const void *lg, *lb, *tp, *sh, *ch;
  const int *lf, *lt;
  int bf;
};
struct LineY { int f, t; float ffr, ffi, ttr, tti, ftr, fti, tfr, tfi; };

__device__ __forceinline__ LineY line_y(const In& I, int l) {
  LineY L;
  float g = rdf(I.lg, l, I.bf), b = rdf(I.lb, l, I.bf);
  float t = rdf(I.tp, l, I.bf), s = rdf(I.sh, l, I.bf);
  float c = rdf(I.ch, l, I.bf) * 0.5f;
  float sn, cs;
  __sincosf(s, &sn, &cs);
  float it = 1.0f / t, it2 = it * it;
  L.f = I.lf[l]; L.t = I.lt[l];
  L.ffr = g * it2;                 L.ffi = (b + c) * it2;
  L.ttr = g;                       L.tti = b + c;
  L.ftr = -(g * cs - b * sn) * it; L.fti = -(g * sn + b * cs) * it;
  L.tfr = -(g * cs + b * sn) * it; L.tfi = -(b * cs - g * sn) * it;
  return L;
}

// y += Y_lines * x (complex, LDS atomics)
__device__ __forceinline__ void coo_apply(const In& I, const float* xr, const float* xi,
                                          float* yr, float* yi) {
  for (int l = threadIdx.x; l < NLINE; l += NTH) {
    LineY L = line_y(I, l);
    float ar = xr[L.f], ai = xi[L.f], br = xr[L.t], bi = xi[L.t];
    atomicAdd(&yr[L.f], L.ffr*ar - L.ffi*ai + L.ftr*br - L.fti*bi);
    atomicAdd(&yi[L.f], L.ffr*ai + L.ffi*ar + L.ftr*bi + L.fti*br);
    atomicAdd(&yr[L.t], L.tfr*ar - L.tfi*ai + L.ttr*br - L.tti*bi);
    atomicAdd(&yi[L.t], L.tfr*ai + L.tfi*ar + L.ttr*bi + L.tti*br);
  }
}
// adjoint
__device__ __forceinline__ void coo_applyT(const In& I, const float* cb, const float* db,
                                           float* ab, float* bb) {
  for (int l = threadIdx.x; l < NLINE; l += NTH) {
    LineY L = line_y(I, l);
    float cf = cb[L.f], df = db[L.f], ct = cb[L.t], dt = db[L.t];
    atomicAdd(&ab[L.f], L.ffr*cf + L.ffi*df + L.tfr*ct + L.tfi*dt);
    atomicAdd(&bb[L.f], -L.ffi*cf + L.ffr*df - L.tfi*ct + L.tfr*dt);
    atomicAdd(&ab[L.t], L.ttr*ct + L.tti*dt + L.ftr*cf + L.fti*df);
    atomicAdd(&bb[L.t], -L.tti*ct + L.ttr*dt - L.fti*cf + L.ftr*df);
  }
}

// off-diagonal per-entry contribution to diag(J^T J): column of bus k, rows of bus i
__device__ __forceinline__ void diag_offentry(int i, int k, float G, float B,
                                              const float* a_, const float* b_,
                                              const float* ca_, const float* sa_,
                                              const int* vmp, const int* vap, float* acc) {
  float ai = a_[i], bi = b_[i];
  float pm = (vap[i] >= 0) ? 1.f : 0.f;
  float qm = (vmp[i] >= 0) ? 1.f : 0.f;
  // dS_i/dVm_k = V_i conj(Y) e^{-i th_k}
  float mr = G * ca_[k] - B * sa_[k];
  float mi = -(G * sa_[k] + B * ca_[k]);
  float ur = ai * mr - bi * mi, ui = ai * mi + bi * mr;
  int vk = vmp[k];
  if (vk >= 0) atomicAdd(&acc[vk], pm * ur * ur + qm * ui * ui);
  // dS_i/dth_k: Re = zi, Im = -zr with z = V_i conj(Y V_k)
  float wr = G * a_[k] - B * b_[k], wi = G * b_[k] + B * a_[k];
  float zr = ai * wr + bi * wi, zi = bi * wr - ai * wi;
  int ak = vap[k];
  if (ak >= 0) atomicAdd(&acc[NNG + ak], pm * zi * zi + qm * zr * zr);
}

__device__ __forceinline__ double blk_sum_d(double v, double* red) {
#pragma unroll
  for (int o = 32; o > 0; o >>= 1) v += __shfl_down(v, o, 64);
  __syncthreads();
  if ((threadIdx.x & 63) == 0) red[threadIdx.x >> 6] = v;
  __syncthreads();
  double s = 0.0;
#pragma unroll
  for (int w = 0; w < NWAVE; ++w) s += red[w];
  return s;
}

// ---- setup -----------------------------------------------------------------
__global__ void setup_k(const void* lg, const void* Pg, const void* Vg,
                        const void* Pl, const void* Ql,
                        const int* gen_b, const int* load_b, const int* refp,
                        Ws* __restrict__ W) {
  int bf = detect_bf(lg);
  int t = blockIdx.x * blockDim.x + threadIdx.x;
  int ref = refp[0];
  if (t < NBUS) {
    int gl = lbound(gen_b, NGEN, t);
    int isg = (gl < NGEN && gen_b[gl] == t) ? 1 : 0;
    int ll = lbound(load_b, NLOAD, t);
    int isl = (ll < NLOAD && load_b[ll] == t) ? 1 : 0;
    W->vm_pos[t] = isg ? -1 : (t - gl);
    W->va_pos[t] = (t == ref) ? -1 : (t - ((t > ref) ? 1 : 0));
    float ps = 0.f, qs = 0.f;
    if (isg) ps += rdf(Pg, gl, bf);
    if (isl) { ps += rdf(Pl, ll, bf); qs += rdf(Ql, ll, bf); }
    W->Pspec[t] = ps;
    W->Qspec[t] = qs;
    W->Vgb[t] = isg ? rdf(Vg, gl, bf) : 1.0f;
  }
}

// ---- the whole solve in one workgroup --------------------------------------
__global__ void __launch_bounds__(NTH, 1)
solver_k(const void* lg, const void* lb, const void* shg, const void* shb,
         const void* tp, const void* sh, const void* ch, const void* limits,
         const int* lf, const int* lt, const int* gen_b, const int* refp,
         const Ws* __restrict__ W, void* __restrict__ out) {
  __shared__ float a_[NBUS], b_[NBUS], c_[NBUS], d_[NBUS], ca_[NBUS], sa_[NBUS];
  __shared__ float Gk_[NBUS], Bk_[NBUS];
  __shared__ float t0_[NBUS], t1_[NBUS], t2_[NBUS], t3_[NBUS];
  __shared__ float x_[NX], q_[NX], g_[NX], p_[NX], dx_[NX], g0_[NX], Mi_[NX];
  __shared__ double red_[NWAVE];

  const int tid = threadIdx.x;
  In I;
  I.lg = lg; I.lb = lb; I.tp = tp; I.sh = sh; I.ch = ch;
  I.lf = lf; I.lt = lt;
  I.bf = detect_bf(lg);
  const int bf = I.bf;
  const int* vmp = W->vm_pos;
  const int* vap = W->va_pos;

  // x init (flat start) + constant Y_kk accumulation (once)
  for (int j = tid; j < NX; j += NTH) x_[j] = (j < NNG) ? 1.0f : 0.0f;
  for (int i = tid; i < NBUS; i += NTH) {
    Gk_[i] = rdf(shg, i, bf);
    Bk_[i] = rdf(shb, i, bf);
  }
  __syncthreads();
  for (int l = tid; l < NLINE; l += NTH) {
    LineY L = line_y(I, l);
    atomicAdd(&Gk_[L.f], L.ffr); atomicAdd(&Bk_[L.f], L.ffi);
    atomicAdd(&Gk_[L.t], L.ttr); atomicAdd(&Bk_[L.t], L.tti);
  }
  __syncthreads();

  // JVP: q_ = J * v   (uses state a_,b_,c_,d_,ca_,sa_; clobbers t0_..t3_)
  auto JVP = [&](const float* v) {
    for (int i = tid; i < NBUS; i += NTH) {
      int vp = vmp[i], ap = vap[i];
      float dVm = (vp >= 0) ? v[vp] : 0.f;
      float dVa = (ap >= 0) ? v[NNG + ap] : 0.f;
      float da = dVm * ca_[i] - dVa * b_[i];
      float db = dVm * sa_[i] + dVa * a_[i];
      t0_[i] = da; t1_[i] = db;
      float gs = rdf(shg, i, bf), bs = rdf(shb, i, bf);
      t2_[i] = gs * da - bs * db;
      t3_[i] = gs * db + bs * da;
    }
    __syncthreads();
    coo_apply(I, t0_, t1_, t2_, t3_);
    __syncthreads();
    for (int i = tid; i < NBUS; i += NTH) {
      float da = t0_[i], db = t1_[i], dc = t2_[i], dd = t3_[i];
      float dP = da*c_[i] + a_[i]*dc + db*d_[i] + b_[i]*dd;
      float dQ = db*c_[i] + b_[i]*dc - da*d_[i] - a_[i]*dd;
      int ap = vap[i], vp = vmp[i];
      if (ap >= 0) q_[ap] = dP;
      if (vp >= 0) q_[NNR + vp] = dQ;
    }
    __syncthreads();
  };

  // VJP front half: seeds from row-vector w, adjoint line pass.
  // After this, per-bus adjoints are in t0_(abar), t1_(bbar); consumer maps to cols.
  auto VJP_pre = [&](const float* w) {
    for (int i = tid; i < NBUS; i += NTH) {
      int ap = vap[i], vp = vmp[i];
      float wP = (ap >= 0) ? w[ap] : 0.f;
      float wQ = (vp >= 0) ? w[NNR + vp] : 0.f;
      float ai = a_[i], bi = b_[i], ci = c_[i], di = d_[i];
      float cb = wP*ai + wQ*bi;
      float db2 = wP*bi - wQ*ai;
      t2_[i] = cb; t3_[i] = db2;
      float gs = rdf(shg, i, bf), bs = rdf(shb, i, bf);
      t0_[i] = wP*ci - wQ*di + gs*cb + bs*db2;
      t1_[i] = wP*di + wQ*ci - bs*cb + gs*db2;
    }
    __syncthreads();
    coo_applyT(I, t2_, t3_, t0_, t1_);
    __syncthreads();
  };

  for (int outer = 0; outer < MAXSTEPS; ++outer) {
    // (a) state -> V, cos/sin; shunt-diag folded into I init
    for (int i = tid; i < NBUS; i += NTH) {
      int vp = vmp[i], ap = vap[i];
      float Vm = (vp >= 0) ? x_[vp] : W->Vgb[i];
      float Va = (ap >= 0) ? x_[NNG + ap] : 0.f;
      float sn, cs;
      __sincosf(Va, &sn, &cs);
      ca_[i] = cs; sa_[i] = sn;
      float av = Vm * cs, bv = Vm * sn;
      a_[i] = av; b_[i] = bv;
      float gs = rdf(shg, i, bf), bs = rdf(shb, i, bf);
      c_[i] = gs * av - bs * bv;
      d_[i] = gs * bv + bs * av;
    }
    __syncthreads();
    coo_apply(I, a_, b_, c_, d_);
    __syncthreads();
    // (c) residual rows -> q_; zero diag accumulator g_
    for (int i = tid; i < NBUS; i += NTH) {
      float P = a_[i]*c_[i] + b_[i]*d_[i] - W->Pspec[i];
      float Q = b_[i]*c_[i] - a_[i]*d_[i] - W->Qspec[i];
      int ap = vap[i], vp = vmp[i];
      if (ap >= 0) q_[ap] = P;
      if (vp >= 0) q_[NNR + vp] = Q;
    }
    for (int j = tid; j < NX; j += NTH) g_[j] = 0.f;
    __syncthreads();
    // (d) exact diag(J^T J): off-diagonal line entries (atomic), then compound own column
    for (int l = tid; l < NLINE; l += NTH) {
      LineY L = line_y(I, l);
      diag_offentry(L.f, L.t, L.ftr, L.fti, a_, b_, ca_, sa_, vmp, vap, g_);
      diag_offentry(L.t, L.f, L.tfr, L.tfi, a_, b_, ca_, sa_, vmp, vap, g_);
    }
    __syncthreads();
    for (int i = tid; i < NBUS; i += NTH) {
      float ai = a_[i], bi = b_[i], ci = c_[i], di = d_[i];
      float G = Gk_[i], B = Bk_[i];
      float pm = (vap[i] >= 0) ? 1.f : 0.f;
      float qm = (vmp[i] >= 0) ? 1.f : 0.f;
      int vp = vmp[i], ap = vap[i];
      // d S_i / d Vm_i = e^{j th} conj(I_i) + V_i conj(Y_kk) e^{-j th}
      float w1r = ca_[i]*ci + sa_[i]*di, w1i = sa_[i]*ci - ca_[i]*di;
      float mr = G*ca_[i] - B*sa_[i],  mi = -(G*sa_[i] + B*ca_[i]);
      float ur = ai*mr - bi*mi, ui = ai*mi + bi*mr;
      float Tr = w1r + ur, Ti = w1i + ui;
      if (vp >= 0) g_[vp] += pm*Tr*Tr + qm*Ti*Ti;
      // d S_i / d th_i = j V conj(I) - j V conj(Y_kk V)
      float w2r = ai*di - bi*ci, w2i = ai*ci + bi*di;
      float wr = G*ai - B*bi, wi = G*bi + B*ai;
      float zr = ai*wr + bi*wi, zi = bi*wr - ai*wi;
      float Ur = w2r + zi, Ui = w2i - zr;
      if (ap >= 0) g_[NNG + ap] += pm*Ur*Ur + qm*Ui*Ui;
    }
    __syncthreads();
    for (int j = tid; j < NX; j += NTH) Mi_[j] = 1.0f / (g_[j] + RIDGE_F);
    __syncthreads();
    // (e) g0 = J^T r
    VJP_pre(q_);
    for (int i = tid; i < NBUS; i += NTH) {
      float ab = t0_[i], bb = t1_[i];
      float tvm = ab*ca_[i] + bb*sa_[i];
      float tva = -ab*b_[i] + bb*a_[i];
      int vp = vmp[i], ap = vap[i];
      if (vp >= 0) g0_[vp] = tvm;
      if (ap >= 0) g0_[NNG + ap] = tva;
    }
    __syncthreads();
    // CG init
    double part = 0.0;
    for (int j = tid; j < NX; j += NTH) {
      g_[j] = g0_[j];
      dx_[j] = 0.f;
      float z = Mi_[j] * g0_[j];
      p_[j] = z;
      part += (double)g0_[j] * (double)z;
    }
    double gamma = blk_sum_d(part, red_);
    const double gamma0 = gamma;

    if (gamma0 > 0.0) {
      for (int it = 0; it < KCG_MAX; ++it) {
        JVP(p_);
        double dpart = 0.0;
        for (int j = tid; j < NX; j += NTH)
          dpart += (double)q_[j]*(double)q_[j] + (double)RIDGE_F*(double)p_[j]*(double)p_[j];
        double delta = blk_sum_d(dpart, red_);
        double alpha = gamma / ((delta > 1e-300) ? delta : 1e-300);
        float af = (float)alpha;
        for (int j = tid; j < NX; j += NTH) dx_[j] += af * p_[j];
        // g -= alpha (J^T q + ridge p)
        VJP_pre(q_);
        for (int i = tid; i < NBUS; i += NTH) {
          float ab = t0_[i], bb = t1_[i];
          float tvm = ab*ca_[i] + bb*sa_[i];
          float tva = -ab*b_[i] + bb*a_[i];
          int vp = vmp[i], ap = vap[i];
          if (vp >= 0) g_[vp] -= af * (tvm + RIDGE_F * p_[vp]);
          if (ap >= 0) g_[NNG + ap] -= af * (tva + RIDGE_F * p_[NNG + ap]);
        }
        __syncthreads();
        if ((it & 63) == 62) {
          // residual replacement: g = g0 - (J^T J + ridge) dx
          JVP(dx_);
          VJP_pre(q_);
          for (int i = tid; i < NBUS; i += NTH) {
            float ab = t0_[i], bb = t1_[i];
            float tvm = ab*ca_[i] + bb*sa_[i];
            float tva = -ab*b_[i] + bb*a_[i];
            int vp = vmp[i], ap = vap[i];
            if (vp >= 0) g_[vp] = g0_[vp] - tvm - RIDGE_F * dx_[vp];
            if (ap >= 0) g_[NNG + ap] = g0_[NNG + ap] - tva - RIDGE_F * dx_[NNG + ap];
          }
          __syncthreads();
        }
        double gpart = 0.0;
        for (int j = tid; j < NX; j += NTH)
          gpart += (double)g_[j] * (double)Mi_[j] * (double)g_[j];
        double gamma2 = blk_sum_d(gpart, red_);
        if (gamma2 <= gamma0 * 1e-12 || gamma2 <= 0.0) break;
        float bfac = (float)(gamma2 / gamma);
        for (int j = tid; j < NX; j += NTH) p_[j] = Mi_[j]*g_[j] + bfac*p_[j];
        gamma = gamma2;
        __syncthreads();
      }
    }
    // apply step
    for (int j = tid; j < NX; j += NTH) x_[j] -= dx_[j];
    __syncthreads();
  }

  // ---- final outputs at converged x ----
  for (int i = tid; i < NBUS; i += NTH) {
    int vp = vmp[i], ap = vap[i];
    float Vm = (vp >= 0) ? x_[vp] : W->Vgb[i];
    float Va = (ap >= 0) ? x_[NNG + ap] : 0.f;
    float sn, cs;
    __sincosf(Va, &sn, &cs);
    ca_[i] = cs; sa_[i] = sn;
    float av = Vm * cs, bv = Vm * sn;
    a_[i] = av; b_[i] = bv;
    t0_[i] = Vm; t1_[i] = Va;
    float gs = rdf(shg, i, bf), bs = rdf(shb, i, bf);
    c_[i] = gs * av - bs * bv;
    d_[i] = gs * bv + bs * av;
  }
  __syncthreads();
  coo_apply(I, a_, b_, c_, d_);
  __syncthreads();
  double rpart = 0.0;
  for (int i = tid; i < NBUS; i += NTH) {
    float P = a_[i]*c_[i] + b_[i]*d_[i] - W->Pspec[i];
    float Q = b_[i]*c_[i] - a_[i]*d_[i] - W->Qspec[i];
    t2_[i] = P; t3_[i] = Q;
    float pm = (vap[i] >= 0) ? 1.f : 0.f;
    float qm = (vmp[i] >= 0) ? 1.f : 0.f;
    rpart += (double)(pm * P * P + qm * Q * Q);
  }
  double rsum = blk_sum_d(rpart, red_);   // barriers inside also publish t2_/t3_
  for (int i = tid; i < NBUS; i += NTH) {
    wrf(out, i, t0_[i], bf);                 // Vm
    wrf(out, NBUS + i, t1_[i], bf);          // Va
    float vmin = rdf(limits, 2*i, bf), vmax = rdf(limits, 2*i + 1, bf);
    float viol = fmaxf(t0_[i] - vmax, 0.f) + fmaxf(vmin - t0_[i], 0.f);
    wrf(out, 2103 + i, viol, bf);            // V_violation
  }
  for (int j = tid; j < NGEN; j += NTH)
    wrf(out, 2000 + j, t3_[gen_b[j]], bf);   // Q_gen (Qspec=0 at gens)
  if (tid == 0) {
    int ref = refp[0];
    wrf(out, 2100, t2_[ref], bf);            // P_ref
    wrf(out, 2101, t3_[ref], bf);            // Q_ref
    wrf(out, 2102, (float)rsum, bf);         // acopf_residual
  }
}

extern "C" void kernel_launch(void* const* d_in, const int* in_sizes, int n_in,
                              void* d_out, int out_size, void* d_ws, size_t ws_size,
                              hipStream_t stream) {
  const void* line_g   = d_in[0];
  const void* line_b   = d_in[1];
  const void* shunt_g  = d_in[2];
  const void* shunt_b  = d_in[3];
  const void* tap      = d_in[4];
  const void* shift    = d_in[5];
  const void* charging = d_in[6];
  const void* P_gen    = d_in[7];
  const void* V_gen    = d_in[8];
  const void* P_load   = d_in[9];
  const void* Q_load   = d_in[10];
  const void* limits   = d_in[11];
  const int* line_from = (const int*)d_in[12];
  const int* line_to   = (const int*)d_in[13];
  const int* gen_b     = (const int*)d_in[14];
  const int* load_b    = (const int*)d_in[15];
  const int* refp      = (const int*)d_in[18];

  if (ws_size < sizeof(Ws)) return;
  Ws* W = (Ws*)d_ws;

  setup_k<<<dim3(8), dim3(256), 0, stream>>>(line_g, P_gen, V_gen, P_load, Q_load,
                                             gen_b, load_b, refp, W);
  solver_k<<<dim3(1), dim3(NTH), 0, stream>>>(line_g, line_b, shunt_g, shunt_b,
                                              tap, shift, charging, limits,
                                              line_from, line_to, gen_b, refp,
                                              W, d_out);
}

// Round 3
// 4364.302 us; speedup vs baseline: 8.7668x; 8.7668x over previous
//
#include <hip/hip_runtime.h>
#include <hip/hip_bf16.h>

// ACOPF Gauss-Newton, matrix-free CGLS, single-workgroup LDS-resident solver.
// R3: CSR adjacency precomputed in LDS (no global loads / sincos in hot loop),
// gather form (no atomics), all CG vectors in per-thread registers (thread i
// owns bus i), block-Jacobi 2x2 preconditioner, 4 barriers per CG iteration.

#define NBUS 1000
#define NLINE 2000
#define NE   (2*NLINE)
#define NGEN 100
#define NLOAD 500
#define NTH 1024
#define NWAVE (NTH/64)
#define MAXSTEPS 10
#define KCG_MAX 500
#define RIDGE_F 1e-6f
#define TOL_REL 1e-10

struct Ws {
  int   vm_pos[NBUS];   // rank in nongen list, or -1 if gen bus
  int   va_pos[NBUS];   // rank in nonref list, or -1 if ref bus
  float Pspec[NBUS];
  float Qspec[NBUS];
  float Vgb[NBUS];
};

// ---- dtype-robust load/store (auto-detected bf16 vs f32) -------------------
__device__ __forceinline__ float rdf(const void* p, int i, int bf) {
  if (bf) {
    unsigned int u = ((unsigned int)(((const unsigned short*)p)[i])) << 16;
    return __uint_as_float(u);
  }
  return ((const float*)p)[i];
}
__device__ __forceinline__ void wrf(void* p, int i, float v, int bf) {
  if (bf) {
    unsigned int u = __float_as_uint(v);
    unsigned int r = (u + 0x7fffu + ((u >> 16) & 1u)) >> 16;  // RNE
    ((unsigned short*)p)[i] = (unsigned short)r;
  } else {
    ((float*)p)[i] = v;
  }
}
__device__ __forceinline__ int detect_bf(const void* p) {
  const unsigned short* h = (const unsigned short*)p;
  int ok = 1;
#pragma unroll
  for (int i = 0; i < 8; ++i) {
    float v = __uint_as_float(((unsigned int)h[i]) << 16);
    ok &= (v > 0.25f && v < 8.0f) ? 1 : 0;
  }
  return ok;
}
__device__ __forceinline__ int lbound(const int* a, int n, int v) {
  int lo = 0, hi = n;
  while (lo < hi) { int m = (lo + hi) >> 1; if (a[m] < v) lo = m + 1; else hi = m; }
  return lo;
}

// ---- line admittance (used ONCE at CSR build) ------------------------------
struct In {
  const void *lg, *lb, *tp, *sh, *ch;
  const int *lf, *lt;
  int bf;
};
struct LineY { int f, t; float ffr, ffi, ttr, tti, ftr, fti, tfr, tfi; };

__device__ __forceinline__ LineY line_y(const In& I, int l) {
  LineY L;
  float g = rdf(I.lg, l, I.bf), b = rdf(I.lb, l, I.bf);
  float t = rdf(I.tp, l, I.bf), s = rdf(I.sh, l, I.bf);
  float c = rdf(I.ch, l, I.bf) * 0.5f;
  float sn, cs;
  __sincosf(s, &sn, &cs);
  float it = 1.0f / t, it2 = it * it;
  L.f = I.lf[l]; L.t = I.lt[l];
  L.ffr = g * it2;                 L.ffi = (b + c) * it2;
  L.ttr = g;                       L.tti = b + c;
  L.ftr = -(g * cs - b * sn) * it; L.fti = -(g * sn + b * cs) * it;
  L.tfr = -(g * cs + b * sn) * it; L.tfi = -(b * cs - g * sn) * it;
  return L;
}

// single-barrier block sum; caller alternates red buffers (ping-pong)
__device__ __forceinline__ double blk_sum1(double v, double* red) {
#pragma unroll
  for (int o = 32; o > 0; o >>= 1) v += __shfl_down(v, o, 64);
  if ((threadIdx.x & 63) == 0) red[threadIdx.x >> 6] = v;
  __syncthreads();
  double s = 0.0;
#pragma unroll
  for (int w = 0; w < NWAVE; ++w) s += red[w];
  return s;
}

// ---- setup -----------------------------------------------------------------
__global__ void setup_k(const void* lg, const void* Pg, const void* Vg,
                        const void* Pl, const void* Ql,
                        const int* gen_b, const int* load_b, const int* refp,
                        Ws* __restrict__ W) {
  int bf = detect_bf(lg);
  int t = blockIdx.x * blockDim.x + threadIdx.x;
  int ref = refp[0];
  if (t < NBUS) {
    int gl = lbound(gen_b, NGEN, t);
    int isg = (gl < NGEN && gen_b[gl] == t) ? 1 : 0;
    int ll = lbound(load_b, NLOAD, t);
    int isl = (ll < NLOAD && load_b[ll] == t) ? 1 : 0;
    W->vm_pos[t] = isg ? -1 : (t - gl);
    W->va_pos[t] = (t == ref) ? -1 : (t - ((t > ref) ? 1 : 0));
    float ps = 0.f, qs = 0.f;
    if (isg) ps += rdf(Pg, gl, bf);
    if (isl) { ps += rdf(Pl, ll, bf); qs += rdf(Ql, ll, bf); }
    W->Pspec[t] = ps;
    W->Qspec[t] = qs;
    W->Vgb[t] = isg ? rdf(Vg, gl, bf) : 1.0f;
  }
}

// ---- the whole solve in one workgroup --------------------------------------
__global__ void __launch_bounds__(NTH)
solver_k(const void* lg, const void* lb, const void* shg, const void* shb,
         const void* tp, const void* sh, const void* ch, const void* limits,
         const int* lf, const int* lt, const int* gen_b, const int* refp,
         const Ws* __restrict__ W, void* __restrict__ out) {
  __shared__ int rs_[NBUS + 1];          // CSR row starts
  __shared__ int scan_[NTH];             // scan ping
  __shared__ int scan2_[NTH];            // scan pong
  __shared__ int cur_[NBUS];             // fill cursors
  __shared__ unsigned short cidx_[NE];   // CSR col index
  __shared__ float2 fwd_[NE];            // Y_kj  (row k -> col j)
  __shared__ float2 rev_[NE];            // Y_jk  (for adjoint / precond)
  __shared__ float2 ab_[NBUS];           // per-bus V (re,im); diag temp at build
  __shared__ float2 sc_[NBUS];           // staging: dV / adjoint seeds / final PQ
  __shared__ float2 mk_[NBUS];           // per-bus masks (mnr, mng)
  __shared__ double red_[2][NWAVE];

  const int tid = threadIdx.x;
  const bool own = (tid < NBUS);
  In I;
  I.lg = lg; I.lb = lb; I.tp = tp; I.sh = sh; I.ch = ch;
  I.lf = lf; I.lt = lt;
  I.bf = detect_bf(lg);
  const int bf = I.bf;

  // --- per-bus constants into registers ---
  int vp = -1, ap = -1;
  float mng = 0.f, mnr = 0.f, Pspec = 0.f, Qspec = 0.f, Vgb = 1.f;
  if (own) {
    vp = W->vm_pos[tid]; ap = W->va_pos[tid];
    mng = (vp >= 0) ? 1.f : 0.f;   // non-gen: Vm unknown exists, Q row exists
    mnr = (ap >= 0) ? 1.f : 0.f;   // non-ref: Va unknown exists, P row exists
    Pspec = W->Pspec[tid]; Qspec = W->Qspec[tid]; Vgb = W->Vgb[tid];
    mk_[tid] = make_float2(mnr, mng);
    ab_[tid] = make_float2(rdf(shg, tid, bf), rdf(shb, tid, bf)); // diag accum init
  }
  // --- degree count ---
  scan_[tid] = 0;
  __syncthreads();
  for (int l = tid; l < NLINE; l += NTH) {
    atomicAdd(&scan_[lf[l]], 1);
    atomicAdd(&scan_[lt[l]], 1);
  }
  __syncthreads();
  // --- inclusive scan (Hillis-Steele, ping-pong) ---
  {
    int* src = scan_; int* dst = scan2_;
    for (int off = 1; off < NTH; off <<= 1) {
      int v = src[tid] + ((tid >= off) ? src[tid - off] : 0);
      dst[tid] = v;
      __syncthreads();
      int* t = src; src = dst; dst = t;
    }
    if (tid == 0) rs_[0] = 0;
    if (own) rs_[tid + 1] = src[tid];
  }
  __syncthreads();
  if (own) cur_[tid] = rs_[tid];
  __syncthreads();
  // --- fill CSR + accumulate diag Y_kk (once; only global loads in kernel) ---
  for (int l = tid; l < NLINE; l += NTH) {
    LineY L = line_y(I, l);
    int pf = atomicAdd(&cur_[L.f], 1);
    cidx_[pf] = (unsigned short)L.t;
    fwd_[pf] = make_float2(L.ftr, L.fti);
    rev_[pf] = make_float2(L.tfr, L.tfi);
    int pt = atomicAdd(&cur_[L.t], 1);
    cidx_[pt] = (unsigned short)L.f;
    fwd_[pt] = make_float2(L.tfr, L.tfi);
    rev_[pt] = make_float2(L.ftr, L.fti);
    atomicAdd(&ab_[L.f].x, L.ffr); atomicAdd(&ab_[L.f].y, L.ffi);
    atomicAdd(&ab_[L.t].x, L.ttr); atomicAdd(&ab_[L.t].y, L.tti);
  }
  __syncthreads();
  float Gkk = 0.f, Bkk = 0.f;
  int rs0 = 0, rs1 = 0;
  if (own) { Gkk = ab_[tid].x; Bkk = ab_[tid].y; rs0 = rs_[tid]; rs1 = rs_[tid + 1]; }
  __syncthreads();

  // --- solver state (registers) ---
  float xvm = 1.f, xva = 0.f;
  int par = 0;

  for (int outer = 0; outer < MAXSTEPS; ++outer) {
    float av = 0.f, bv = 0.f, ca = 1.f, sa = 0.f, cI = 0.f, dI = 0.f;
    float wP = 0.f, wQ = 0.f;
    if (own) {
      float Vm = (vp >= 0) ? xvm : Vgb;
      float Va = (ap >= 0) ? xva : 0.f;
      __sincosf(Va, &sa, &ca);
      av = Vm * ca; bv = Vm * sa;
      ab_[tid] = make_float2(av, bv);
    }
    __syncthreads();
    if (own) {
      cI = Gkk * av - Bkk * bv; dI = Gkk * bv + Bkk * av;
      for (int e = rs0; e < rs1; ++e) {
        int j = cidx_[e]; float2 f = fwd_[e], v = ab_[j];
        cI += f.x * v.x - f.y * v.y; dI += f.x * v.y + f.y * v.x;
      }
      float P = av * cI + bv * dI - Pspec;
      float Q = bv * cI - av * dI - Qspec;
      wP = mnr * P; wQ = mng * Q;
    }
    // --- block-Jacobi 2x2 of (J^T J): exact per-bus Gram block ---
    float M11 = 0.f, M12 = 0.f, M22 = 0.f;
    if (own) {
      float w1r = ca * cI + sa * dI, w1i = sa * cI - ca * dI;
      float mr = Gkk * ca - Bkk * sa, mi = -(Gkk * sa + Bkk * ca);
      float ur0 = av * mr - bv * mi, ui0 = av * mi + bv * mr;
      float Tr = w1r + ur0, Ti = w1i + ui0;           // dS_k/dVm_k
      float w2r = av * dI - bv * cI, w2i = av * cI + bv * dI;
      float wr0 = Gkk * av - Bkk * bv, wi0 = Gkk * bv + Bkk * av;
      float zr0 = av * wr0 + bv * wi0, zi0 = bv * wr0 - av * wi0;
      float Uor = w2r + zi0, Uoi = w2i - zr0;         // dS_k/dVa_k
      float Avv = mnr * Tr * Tr + mng * Ti * Ti;
      float Aaa = mnr * Uor * Uor + mng * Uoi * Uoi;
      float Ava = mnr * Tr * Uor + mng * Ti * Uoi;
      for (int e = rs0; e < rs1; ++e) {               // neighbor rows' view of col k
        int j = cidx_[e]; float2 r = rev_[e], vj = ab_[j], mj = mk_[j];
        float mrr = r.x * ca - r.y * sa, mii = -(r.x * sa + r.y * ca);
        float ur = vj.x * mrr - vj.y * mii, ui = vj.x * mii + vj.y * mrr;
        float wr = r.x * av - r.y * bv, wi = r.x * bv + r.y * av;
        float zr = vj.x * wr + vj.y * wi, zi = vj.y * wr - vj.x * wi;
        Avv += mj.x * ur * ur + mj.y * ui * ui;
        Aaa += mj.x * zi * zi + mj.y * zr * zr;
        Ava += mj.x * ur * zi - mj.y * ui * zr;
      }
      float A11 = Avv + RIDGE_F, A22 = Aaa + RIDGE_F;
      if (vp >= 0 && ap >= 0) {
        float id = 1.f / (A11 * A22 - Ava * Ava);
        M11 = A22 * id; M22 = A11 * id; M12 = -Ava * id;
      } else if (vp >= 0) M11 = 1.f / A11;
      else if (ap >= 0)  M22 = 1.f / A22;
    }
    // --- g0 = J^T r ---
    float g0vm = 0.f, g0va = 0.f;
    if (own) sc_[tid] = make_float2(wP * av + wQ * bv, wP * bv - wQ * av);
    __syncthreads();
    if (own) {
      float2 s = sc_[tid]; float cb = s.x, db2 = s.y;
      float abar = wP * cI - wQ * dI + Gkk * cb + Bkk * db2;
      float bbar = wP * dI + wQ * cI - Bkk * cb + Gkk * db2;
      for (int e = rs0; e < rs1; ++e) {
        int j = cidx_[e]; float2 r = rev_[e], w = sc_[j];
        abar += r.x * w.x + r.y * w.y; bbar += -r.y * w.x + r.x * w.y;
      }
      g0vm = mng * (abar * ca + bbar * sa);
      g0va = mnr * (-abar * bv + bbar * av);
    }
    float gvm = g0vm, gva = g0va, dxvm = 0.f, dxva = 0.f;
    float zvm = M11 * gvm + M12 * gva, zva = M12 * gvm + M22 * gva;
    float pvm = zvm, pva = zva;
    double part = own ? ((double)gvm * zvm + (double)gva * zva) : 0.0;
    double gamma = blk_sum1(part, red_[par]); par ^= 1;
    const double gamma0 = gamma;

    if (gamma0 > 0.0) {
      for (int it = 0; it < KCG_MAX; ++it) {
        // --- JVP(p): q = J p ---
        float qP = 0.f, qQ = 0.f;
        if (own) sc_[tid] = make_float2(pvm * ca - pva * bv, pvm * sa + pva * av);
        __syncthreads();
        double dpart = 0.0;
        if (own) {
          float2 s = sc_[tid]; float da = s.x, db = s.y;
          float dc = Gkk * da - Bkk * db, dd = Gkk * db + Bkk * da;
          for (int e = rs0; e < rs1; ++e) {
            int j = cidx_[e]; float2 f = fwd_[e], v = sc_[j];
            dc += f.x * v.x - f.y * v.y; dd += f.x * v.y + f.y * v.x;
          }
          float dP = da * cI + av * dc + db * dI + bv * dd;
          float dQ = db * cI + bv * dc - da * dI - av * dd;
          qP = mnr * dP; qQ = mng * dQ;
          dpart = (double)qP * dP + (double)qQ * dQ +
                  (double)RIDGE_F * ((double)pvm * pvm + (double)pva * pva);
        }
        double delta = blk_sum1(dpart, red_[par]); par ^= 1;
        if (!(delta > 0.0)) break;
        float af = (float)(gamma / delta);
        if (own) { dxvm += af * pvm; dxva += af * pva; }
        // --- VJP(q): g -= alpha (J^T q + ridge p) ---
        if (own) sc_[tid] = make_float2(qP * av + qQ * bv, qP * bv - qQ * av);
        __syncthreads();
        if (own) {
          float2 s = sc_[tid]; float cb = s.x, db2 = s.y;
          float abar = qP * cI - qQ * dI + Gkk * cb + Bkk * db2;
          float bbar = qP * dI + qQ * cI - Bkk * cb + Gkk * db2;
          for (int e = rs0; e < rs1; ++e) {
            int j = cidx_[e]; float2 r = rev_[e], w = sc_[j];
            abar += r.x * w.x + r.y * w.y; bbar += -r.y * w.x + r.x * w.y;
          }
          float yvm = mng * (abar * ca + bbar * sa);
          float yva = mnr * (-abar * bv + bbar * av);
          gvm -= af * (yvm + RIDGE_F * pvm);
          gva -= af * (yva + RIDGE_F * pva);
        }
        // --- residual replacement every 64 iters: g = g0 - (J^T J + ridge) dx ---
        if ((it & 63) == 63) {
          if (own) sc_[tid] = make_float2(dxvm * ca - dxva * bv, dxvm * sa + dxva * av);
          __syncthreads();
          float rP = 0.f, rQ = 0.f;
          if (own) {
            float2 s = sc_[tid]; float da = s.x, db = s.y;
            float dc = Gkk * da - Bkk * db, dd = Gkk * db + Bkk * da;
            for (int e = rs0; e < rs1; ++e) {
              int j = cidx_[e]; float2 f = fwd_[e], v = sc_[j];
              dc += f.x * v.x - f.y * v.y; dd += f.x * v.y + f.y * v.x;
            }
            float dP = da * cI + av * dc + db * dI + bv * dd;
            float dQ = db * cI + bv * dc - da * dI - av * dd;
            rP = mnr * dP; rQ = mng * dQ;
          }
          __syncthreads();  // all gathers done before overwriting sc_
          if (own) sc_[tid] = make_float2(rP * av + rQ * bv, rP * bv - rQ * av);
          __syncthreads();
          if (own) {
            float2 s = sc_[tid]; float cb = s.x, db2 = s.y;
            float abar = rP * cI - rQ * dI + Gkk * cb + Bkk * db2;
            float bbar = rP * dI + rQ * cI - Bkk * cb + Gkk * db2;
            for (int e = rs0; e < rs1; ++e) {
              int j = cidx_[e]; float2 r = rev_[e], w = sc_[j];
              abar += r.x * w.x + r.y * w.y; bbar += -r.y * w.x + r.x * w.y;
            }
            float yvm = mng * (abar * ca + bbar * sa);
            float yva = mnr * (-abar * bv + bbar * av);
            gvm = g0vm - yvm - RIDGE_F * dxvm;
            gva = g0va - yva - RIDGE_F * dxva;
          }
        }
        double gpart = 0.0;
        if (own) {
          zvm = M11 * gvm + M12 * gva; zva = M12 * gvm + M22 * gva;
          gpart = (double)gvm * zvm + (double)gva * zva;
        }
        double gamma2 = blk_sum1(gpart, red_[par]); par ^= 1;
        if (gamma2 <= gamma0 * TOL_REL || !(gamma2 > 0.0)) break;
        float bfac = (float)(gamma2 / gamma);
        if (own) { pvm = zvm + bfac * pvm; pva = zva + bfac * pva; }
        gamma = gamma2;
      }
    }
    if (own) { xvm -= dxvm; xva -= dxva; }
    __syncthreads();
  }

  // ---- final outputs ----
  float Vmf = 1.f, Vaf = 0.f, av = 0.f, bv = 0.f, cI = 0.f, dI = 0.f;
  if (own) {
    Vmf = (vp >= 0) ? xvm : Vgb;
    Vaf = (ap >= 0) ? xva : 0.f;
    float sn, cs;
    __sincosf(Vaf, &sn, &cs);
    av = Vmf * cs; bv = Vmf * sn;
    ab_[tid] = make_float2(av, bv);
  }
  __syncthreads();
  float P = 0.f, Q = 0.f;
  if (own) {
    cI = Gkk * av - Bkk * bv; dI = Gkk * bv + Bkk * av;
    for (int e = rs0; e < rs1; ++e) {
      int j = cidx_[e]; float2 f = fwd_[e], v = ab_[j];
      cI += f.x * v.x - f.y * v.y; dI += f.x * v.y + f.y * v.x;
    }
    P = av * cI + bv * dI - Pspec;
    Q = bv * cI - av * dI - Qspec;
    sc_[tid] = make_float2(P, Q);
  }
  __syncthreads();
  double rpart = own ? (double)(mnr * P * P + mng * Q * Q) : 0.0;
  double rsum = blk_sum1(rpart, red_[par]); par ^= 1;
  if (own) {
    wrf(out, tid, Vmf, bf);                  // Vm
    wrf(out, NBUS + tid, Vaf, bf);           // Va
    float vmin = rdf(limits, 2 * tid, bf), vmax = rdf(limits, 2 * tid + 1, bf);
    float viol = fmaxf(Vmf - vmax, 0.f) + fmaxf(vmin - Vmf, 0.f);
    wrf(out, 2103 + tid, viol, bf);          // V_violation
  }
  if (tid < NGEN) wrf(out, 2000 + tid, sc_[gen_b[tid]].y, bf);  // Q_gen
  if (tid == 0) {
    int ref = refp[0];
    wrf(out, 2100, sc_[ref].x, bf);          // P_ref
    wrf(out, 2101, sc_[ref].y, bf);          // Q_ref
    wrf(out, 2102, (float)rsum, bf);         // acopf_residual
  }
}

extern "C" void kernel_launch(void* const* d_in, const int* in_sizes, int n_in,
                              void* d_out, int out_size, void* d_ws, size_t ws_size,
                              hipStream_t stream) {
  const void* line_g   = d_in[0];
  const void* line_b   = d_in[1];
  const void* shunt_g  = d_in[2];
  const void* shunt_b  = d_in[3];
  const void* tap      = d_in[4];
  const void* shift    = d_in[5];
  const void* charging = d_in[6];
  const void* P_gen    = d_in[7];
  const void* V_gen    = d_in[8];
  const void* P_load   = d_in[9];
  const void* Q_load   = d_in[10];
  const void* limits   = d_in[11];
  const int* line_from = (const int*)d_in[12];
  const int* line_to   = (const int*)d_in[13];
  const int* gen_b     = (const int*)d_in[14];
  const int* load_b    = (const int*)d_in[15];
  const int* refp      = (const int*)d_in[18];

  if (ws_size < sizeof(Ws)) return;
  Ws* W = (Ws*)d_ws;

  setup_k<<<dim3(8), dim3(256), 0, stream>>>(line_g, P_gen, V_gen, P_load, Q_load,
                                             gen_b, load_b, refp, W);
  solver_k<<<dim3(1), dim3(NTH), 0, stream>>>(line_g, line_b, shunt_g, shunt_b,
                                              tap, shift, charging, limits,
                                              line_from, line_to, gen_b, refp,
                                              W, d_out);
}